// Round 11
// baseline (23375.433 us; speedup 1.0000x reference)
//
#include <hip/hip_runtime.h>
#include <cmath>

// ResLSTM+CRF on MI355X, fp32 vector-ALU implementation.
// R18 = R15 (proven 10386 us: k4s 256x1024, c-hoist) EXACTLY, + ONE delta:
//   k4b fused into the k4s dispatch chain. feats[tf] depends only on
//   h1h[tf+1], written two dispatches earlier (stream-ordered, guaranteed
//   visible). Each k4s dispatch carries one extra block (grid 257) that
//   computes feats[t-2] with the original k4b math; the chain is extended by
//   one dispatch (t = 0..SS+1) to cover all tf = 0..511; the standalone
//   512-block k4b launch is removed. The extra block co-resides on a CU
//   (16 spare waves) and hides in the inter-dispatch shadow.
// R16's 512x512 k4s split regressed (dispatch ramp > overlap gain) — reverted.
// k2 keeps the R15-proven 1024-thr structure + gbarC protocol unchanged.

namespace {
constexpr int SS = 512;     // seq len
constexpr int BB = 64;      // batch
constexpr int EE = 256;     // embed dim
constexpr int HHd = 256;    // half hidden (bi-lstm)
constexpr int HD = 512;     // hidden (stack)
constexpr int NTAG = 22;
constexpr int TSTART = 20;
constexpr int TSTOP = 21;

// ws offsets (in floats) — IDENTICAL footprint to the proven layout.
constexpr size_t OFF_BI    = 0;                                      // [512][512][64] chunked
constexpr size_t OFF_H1H   = OFF_BI    + (size_t)SS * HD * BB;       // [513][512][64] chunked
constexpr size_t OFF_XT    = OFF_H1H   + (size_t)(SS + 1) * HD * BB; // [512][256][64]; dead after k2 -> k4 c-state
constexpr size_t OFF_FEATS = OFF_XT    + (size_t)SS * EE * BB;       // [512][22][64]
constexpr size_t OFF_H0R   = OFF_FEATS + (size_t)SS * NTAG * BB;     // [2][512][64] ping-pong
constexpr size_t OFF_HF    = OFF_H0R   + 2 * (size_t)HD * BB;        // [2][256][64] (k2, coherent)
constexpr size_t OFF_HB    = OFF_HF    + 2 * (size_t)HHd * BB;
constexpr size_t OFF_BAR   = OFF_HB    + 2 * (size_t)HHd * BB;       // barrier state (ints, k2 only)
constexpr int BAR_INTS = 1152;

// k4 c-state, carved from the dead xT region
constexpr size_t OFF_C0 = OFF_XT;                    // [512][64] chunked (cidx)
constexpr size_t OFF_C1 = OFF_XT + (size_t)HD * BB;  // [512][64] chunked
}

__device__ __forceinline__ int cidx(int k, int lane) {
  return ((k >> 2) << 8) + (lane << 2) + (k & 3);
}

// ---- k2-only coherence helpers (proven; unchanged) ----
__device__ __forceinline__ float4 cload4(const float4* p) {
  float4 r;
  asm volatile("global_load_dwordx4 %0, %1, off sc0 sc1" : "=v"(r) : "v"(p));
  return r;
}
__device__ __forceinline__ void vwait0() {
  asm volatile("s_waitcnt vmcnt(0)" ::: "memory");
}
__device__ __forceinline__ void cstore(float* p, float v) {
  __hip_atomic_store(p, v, __ATOMIC_RELAXED, __HIP_MEMORY_SCOPE_AGENT);
}

// Centralized-release device barrier (k2 only), no fences.
template <int NBLK>
__device__ __forceinline__ void gbarC(int* flags, int* release, int bid, int epoch) {
  __syncthreads();
  if (threadIdx.x == 0) {
    __hip_atomic_store(flags + bid, epoch + 1, __ATOMIC_RELAXED, __HIP_MEMORY_SCOPE_AGENT);
  }
  if (bid == 0) {
    if (threadIdx.x < 64) {
      constexpr int PER = NBLK / 64;
      bool ok;
      do {
        ok = true;
#pragma unroll
        for (int i = 0; i < PER; ++i) {
          ok = ok && (__hip_atomic_load(flags + threadIdx.x * PER + i, __ATOMIC_RELAXED,
                                        __HIP_MEMORY_SCOPE_AGENT) > epoch);
        }
      } while (__any(!ok));
      if (threadIdx.x == 0) {
        __hip_atomic_store(release, epoch + 1, __ATOMIC_RELAXED, __HIP_MEMORY_SCOPE_AGENT);
      }
    }
  } else {
    if (threadIdx.x == 0) {
      while (__hip_atomic_load(release, __ATOMIC_RELAXED, __HIP_MEMORY_SCOPE_AGENT) <= epoch) {
        __builtin_amdgcn_s_sleep(1);
      }
    }
  }
  __syncthreads();
}

__device__ __forceinline__ float sigm(float x) { return 1.f / (1.f + expf(-x)); }
__device__ __forceinline__ float comp4(float4 v, int w) {
  return (w == 0) ? v.x : (w == 1) ? v.y : (w == 2) ? v.z : v.w;
}

// K0: gather embeddings, transpose to chunked [t][e-chunk][lane][4]
__global__ __launch_bounds__(256) void k0(const int* __restrict__ sent,
                                          const float* __restrict__ emb,
                                          float* __restrict__ xT) {
  const int t = blockIdx.x;
  const int lane = threadIdx.x & 63;
  const int w = __builtin_amdgcn_readfirstlane(threadIdx.x >> 6); // 0..3
  __shared__ float tile[64][65];
  __shared__ int rows[64];
  if (threadIdx.x < 64) rows[threadIdx.x] = sent[(size_t)threadIdx.x * SS + t];
  __syncthreads();
  float4* xT4 = (float4*)xT;
  for (int e0 = 0; e0 < EE; e0 += 64) {
    for (int bb = 0; bb < 16; ++bb) {
      int b = bb * 4 + w;
      tile[b][lane] = emb[(size_t)rows[b] * EE + e0 + lane];
    }
    __syncthreads();
    for (int r = 0; r < 4; ++r) {
      int ecl = w * 4 + r;
      int ec = (e0 >> 2) + ecl;
      float4 v = make_float4(tile[lane][ecl * 4 + 0], tile[lane][ecl * 4 + 1],
                             tile[lane][ecl * 4 + 2], tile[lane][ecl * 4 + 3]);
      xT4[((size_t)t * 64 + ec) * 64 + lane] = v;
    }
    __syncthreads();
  }
}

struct K2A {
  const float* xT; float* bi;
  const float* wih_f; const float* whh_f; const float* b_f;
  const float* wih_b; const float* whh_b; const float* b_b;
  const float* h10; const float* c10; const int* lengths;
  float* hf; float* hb;
  int* bar;
};

// K2: BiLSTM. 256 blocks x 1024 thr (16 waves, 4/SIMD). PROVEN R15 structure.
__global__ __launch_bounds__(1024, 1) void k2(K2A a) {
  const int lane = threadIdx.x & 63;
  const int w = __builtin_amdgcn_readfirstlane((int)threadIdx.x >> 6); // 0..15
  const int d = (int)blockIdx.x >> 7;
  const int lb = (int)blockIdx.x & 127;
  int* flags = a.bar + d * 384;
  int* release = a.bar + d * 384 + 160;
  const int u0 = lb * 2;
  const float* wih = d ? a.wih_b : a.wih_f;
  const float* whh = d ? a.whh_b : a.whh_f;
  const float* bias = d ? a.b_b : a.b_f;
  float* hbuf = d ? a.hb : a.hf;

  __shared__ float lw[8 * 512];          // 16 KB: [r][z-k], r = g*2+ul
  __shared__ float4 part[16][2][64];     // 32 KB

  // stage weights: 1024 float4s, 1 per thread
  {
    int f4 = (int)threadIdx.x;           // 0..1023
    int r = f4 >> 7;                     // 128 f4 per row
    int kk = (f4 & 127) * 4;
    int g = r >> 1, ul = r & 1;
    int grow = g * HHd + u0 + ul;
    float4 v = (kk < 256) ? *(const float4*)(wih + (size_t)grow * 256 + kk)
                          : *(const float4*)(whh + (size_t)grow * 256 + (kk - 256));
    *(float4*)(lw + r * 512 + kk) = v;
  }

  const int len = a.lengths[lane];
  float c_st = 0.f, h_old = 0.f;
  if (w < 2) {
    int u = u0 + w;
    h_old = a.h10[d * 256 + u];
    c_st = a.c10[d * 256 + u];
    cstore(&hbuf[cidx(u, lane)], h_old);
    vwait0();
  }
  int ep = 0;
  gbarC<128>(flags, release, lb, ep); ep++;   // entry __syncthreads orders staging

  const int ks = w * 32;                 // z-slice start (0..480)
  const bool hpart = (w >= 8);
  const float4* lw4 = (const float4*)lw;
  int buf = 0;
  for (int step = 0; step < SS; ++step) {
    const int t = d ? (SS - 1 - step) : step;
    const float* actbase = hpart ? (hbuf + (size_t)buf * (HHd * 64))
                                 : (a.xT + (size_t)t * (EE * 64));
    const int ksl = hpart ? (ks - 256) : ks;
    const float4* p = (const float4*)actbase + (size_t)(ksl >> 2) * 64 + lane;
    float4 va[8];
    if (hpart) {
#pragma unroll
      for (int c = 0; c < 8; ++c) va[c] = cload4(p + (size_t)c * 64);
      vwait0();
    } else {
#pragma unroll
      for (int c = 0; c < 8; ++c) va[c] = p[(size_t)c * 64];
    }
    float acc[8] = {0, 0, 0, 0, 0, 0, 0, 0};
#pragma unroll
    for (int c = 0; c < 8; ++c) {
      float4 h = va[c];
#pragma unroll
      for (int r = 0; r < 8; ++r) {
        float4 wv = lw4[r * 128 + (ks >> 2) + c];   // broadcast ds_read_b128
        acc[r] = fmaf(h.x, wv.x, acc[r]);
        acc[r] = fmaf(h.y, wv.y, acc[r]);
        acc[r] = fmaf(h.z, wv.z, acc[r]);
        acc[r] = fmaf(h.w, wv.w, acc[r]);
      }
    }
    part[w][0][lane] = make_float4(acc[0], acc[1], acc[2], acc[3]);
    part[w][1][lane] = make_float4(acc[4], acc[5], acc[6], acc[7]);
    __syncthreads();
    if (w < 2) {
      // acc rows: [0..3] = {i.u0,i.u1,f.u0,f.u1}, [4..7] = {g.u0,g.u1,o.u0,o.u1}
      float qi = 0.f, qf = 0.f, qg = 0.f, qo = 0.f;
#pragma unroll
      for (int wv = 0; wv < 16; ++wv) {
        float4 p0 = part[wv][0][lane], p1 = part[wv][1][lane];
        qi += comp4(p0, w);  qf += comp4(p0, 2 + w);
        qg += comp4(p1, w);  qo += comp4(p1, 2 + w);
      }
      const int u = u0 + w;
      float gi = qi + bias[u];
      float gf = qf + bias[256 + u];
      float gg = qg + bias[512 + u];
      float go = qo + bias[768 + u];
      float i_ = sigm(gi), f_ = sigm(gf), o_ = sigm(go);
      float gn = tanhf(gg);
      float c2 = f_ * c_st + i_ * gn;
      float h2 = o_ * tanhf(c2);
      const bool m = (t < len);
      h2 = m ? h2 : h_old;
      c_st = m ? c2 : c_st;
      h_old = h2;
      cstore(&hbuf[(size_t)(buf ^ 1) * (HHd * 64) + cidx(u, lane)], h2);
      a.bi[(size_t)t * (HD * 64) + cidx(d * 256 + u, lane)] = m ? h2 : 0.f;
      vwait0();
    }
    buf ^= 1;
    gbarC<128>(flags, release, lb, ep); ep++;
  }
}

// K4i: seed h0r[0], h1h[0], c0, c1 from h20/c20 (re-run every call; ws poisoned).
__global__ __launch_bounds__(512) void k4i(const float* __restrict__ h20,
                                           const float* __restrict__ c20,
                                           float* __restrict__ h0r,
                                           float* __restrict__ h1h,
                                           float* __restrict__ c0,
                                           float* __restrict__ c1) {
  const int layer = blockIdx.x;          // 0..1
  const int u = threadIdx.x;             // 0..511
  const float hv = h20[layer * 512 + u];
  const float cv = c20[layer * 512 + u];
  float* hd = layer ? h1h : h0r;
  float* cd = layer ? c1 : c0;
#pragma unroll 4
  for (int lane = 0; lane < 64; ++lane) {
    hd[cidx(u, lane)] = hv;
    cd[cidx(u, lane)] = cv;
  }
}

struct K4S {
  const float* bi; float* h0r; float* h1h;
  const float* wihs; const float* whhs; const float* bs;
  float* c0; float* c1;
  const float* Wtag; const float* btag; float* feats;
};

// K4s: ONE super-step. 257 blocks x 1024 thr. Blocks 0..255: R15-proven layer
// step (layer = bid>>7, 4 units/block, 16 waves x 64-k slices, c-hoist).
// Block 256: fused k4b — computes feats[t-2] from h1h[t-1] (written two
// dispatches earlier; stream-ordered visible) using the original k4b math on
// its first 256 threads. Chain runs t = 0..SS+1 to cover all feats.
__global__ __launch_bounds__(1024, 1) void k4s(K4S a, int t) {
  // ---- fused k4b block ----
  if ((int)blockIdx.x >= 256) {
    const int tf = t - 2;
    if (tf < 0 || tf >= SS) return;
    if ((int)threadIdx.x >= 256) return;
    const int lane = threadIdx.x & 63;
    const int w4 = __builtin_amdgcn_readfirstlane((int)threadIdx.x >> 6); // 0..3
    const int j0 = w4 * 6;
    const float4* p = (const float4*)(a.h1h + (size_t)(tf + 1) * (HD * 64)) + lane;
    const float* r[6];
    float acc[6];
#pragma unroll
    for (int jj = 0; jj < 6; ++jj) {
      int j = j0 + jj; if (j > 21) j = 21;
      r[jj] = a.Wtag + (size_t)j * HD;
      acc[jj] = a.btag[j];
    }
#pragma unroll 2
    for (int c = 0; c < 128; ++c) {
      float4 h = p[(size_t)c * 64];
      int k = c * 4;
#pragma unroll
      for (int jj = 0; jj < 6; ++jj) {
        acc[jj] = fmaf(h.x, r[jj][k], acc[jj]);
        acc[jj] = fmaf(h.y, r[jj][k + 1], acc[jj]);
        acc[jj] = fmaf(h.z, r[jj][k + 2], acc[jj]);
        acc[jj] = fmaf(h.w, r[jj][k + 3], acc[jj]);
      }
    }
#pragma unroll
    for (int jj = 0; jj < 6; ++jj) {
      int j = j0 + jj;
      if (j < NTAG) a.feats[((size_t)tf * NTAG + j) * 64 + lane] = acc[jj];
    }
    return;
  }

  // ---- R15-proven layer step ----
  const int layer = (int)blockIdx.x >> 7;
  if (layer == 0) { if (t >= SS) return; } else { if (t < 1 || t > SS) return; }
  const int lane = threadIdx.x & 63;
  const int w = __builtin_amdgcn_readfirstlane((int)threadIdx.x >> 6);  // 0..15
  const int lb = (int)blockIdx.x & 127;
  const int u0 = lb * 4;
  const float* wih = a.wihs + (size_t)layer * (2048 * 512);
  const float* whh = a.whhs + (size_t)layer * (2048 * 512);

  __shared__ float part[8][16][64];      // 32 KB

  // hoisted c-state load (consumed in the epilogue, ~matmul-length later)
  float* cst = layer ? a.c1 : a.c0;
  float c_st = 0.f;
  if (w < 4) c_st = cst[cidx(u0 + w, lane)];

  const int ks = (w & 7) * 64;           // k-slice start within the 512-k half
  const bool hpart = (w >= 8);
  const float* wsel = hpart ? whh : wih;
  const float* wr[16];
#pragma unroll
  for (int g = 0; g < 4; ++g)
#pragma unroll
    for (int ul = 0; ul < 4; ++ul)
      wr[g * 4 + ul] = wsel + (size_t)(g * HD + u0 + ul) * HD + ks;

  const float* actbase;
  if (layer == 0)
    actbase = hpart ? (a.h0r + (size_t)(t & 1) * (HD * 64))
                    : (a.bi + (size_t)t * (HD * 64));
  else
    actbase = hpart ? (a.h1h + (size_t)(t - 1) * (HD * 64))
                    : (a.h0r + (size_t)(t & 1) * (HD * 64));

  // load this wave's 64-k activation slice (16 float4s)
  const float4* p = (const float4*)actbase + (size_t)(ks >> 2) * 64 + lane;
  float4 va[16];
#pragma unroll
  for (int c = 0; c < 16; ++c) va[c] = p[(size_t)c * 64];

  float acc[16] = {0, 0, 0, 0, 0, 0, 0, 0, 0, 0, 0, 0, 0, 0, 0, 0};
#pragma unroll
  for (int c = 0; c < 16; ++c) {
    float4 h = va[c];
    const int k = c * 4;
#pragma unroll
    for (int r = 0; r < 16; ++r) {
      float4 wv = *(const float4*)(wr[r] + k);      // cached global (uniform)
      acc[r] = fmaf(h.x, wv.x, acc[r]);
      acc[r] = fmaf(h.y, wv.y, acc[r]);
      acc[r] = fmaf(h.z, wv.z, acc[r]);
      acc[r] = fmaf(h.w, wv.w, acc[r]);
    }
  }
  // 2-stage cross-wave reduction: waves 0-7 write, waves 8-15 add.
  if (w < 8) {
#pragma unroll
    for (int r = 0; r < 16; ++r) part[w][r][lane] = acc[r];
  }
  __syncthreads();
  if (w >= 8) {
#pragma unroll
    for (int r = 0; r < 16; ++r) part[w - 8][r][lane] += acc[r];
  }
  __syncthreads();
  if (w < 4) {
    float q[4];
#pragma unroll
    for (int g = 0; g < 4; ++g) {
      float s = 0.f;
#pragma unroll
      for (int sl = 0; sl < 8; ++sl) s += part[sl][g * 4 + w][lane];
      q[g] = s;
    }
    const int u = u0 + w;
    const float* bsl = a.bs + (size_t)layer * 2048;
    float gi = q[0] + bsl[u];
    float gf = q[1] + bsl[512 + u];
    float gg = q[2] + bsl[1024 + u];
    float go = q[3] + bsl[1536 + u];
    float i_ = sigm(gi), f_ = sigm(gf), o_ = sigm(go);
    float gn = tanhf(gg);
    float c2 = f_ * c_st + i_ * gn;
    float h2 = o_ * tanhf(c2);
    cst[cidx(u, lane)] = c2;
    if (layer == 0)
      a.h0r[(size_t)((t + 1) & 1) * (HD * 64) + cidx(u, lane)] = h2;
    else
      a.h1h[(size_t)t * (HD * 64) + cidx(u, lane)] = h2;
  }
}

// K5: Viterbi decode, one block per batch element, backpointers in LDS.
__global__ __launch_bounds__(64) void k5(const float* __restrict__ feats,
                                         const float* __restrict__ trans,
                                         const int* __restrict__ lengths,
                                         float* __restrict__ out) {
  const int b = blockIdx.x;
  const int j = threadIdx.x;
  __shared__ float tr[NTAG * NTAG];
  __shared__ float sc[NTAG];
  __shared__ float term[NTAG];
  __shared__ unsigned char bp[SS - 1][NTAG];
  for (int i = j; i < NTAG * NTAG; i += 64) tr[i] = trans[i];
  const int len = lengths[b];
  float score = 0.f;
  __syncthreads();
  if (j < NTAG) {
    score = feats[(size_t)j * 64 + b] + tr[j * NTAG + TSTART];
    sc[j] = score;
  }
  __syncthreads();
  for (int t = 1; t < len; ++t) {
    float best = -3.4e38f; int bi_ = 0;
    if (j < NTAG) {
#pragma unroll
      for (int i = 0; i < NTAG; ++i) {
        float c = sc[i] + tr[j * NTAG + i];
        if (c > best) { best = c; bi_ = i; }   // strict > keeps first max
      }
      score = best + feats[((size_t)t * NTAG + j) * 64 + b];
      bp[t - 1][j] = (unsigned char)bi_;
    }
    __syncthreads();
    if (j < NTAG) sc[j] = score;
    __syncthreads();
  }
  if (j < NTAG) term[j] = score + tr[TSTOP * NTAG + j];
  __syncthreads();
  if (j == 0) {
    float bs = term[0]; int bt = 0;
    for (int i = 1; i < NTAG; ++i) if (term[i] > bs) { bs = term[i]; bt = i; }
    out[b] = bs;
    int tag = bt;
    for (int t = SS - 1; t >= 1; --t) {
      out[64 + (size_t)b * SS + t] = (float)tag;
      if (t < len) tag = bp[t - 1][tag];
    }
    out[64 + (size_t)b * SS + 0] = (float)tag;
  }
}

extern "C" void kernel_launch(void* const* d_in, const int* in_sizes, int n_in,
                              void* d_out, int out_size, void* d_ws, size_t ws_size,
                              hipStream_t stream) {
  const int* sentence = (const int*)d_in[0];
  const int* lengths  = (const int*)d_in[1];
  const float* emb    = (const float*)d_in[2];
  const float* wih_f  = (const float*)d_in[3];
  const float* whh_f  = (const float*)d_in[4];
  const float* b_f    = (const float*)d_in[5];
  const float* wih_b  = (const float*)d_in[6];
  const float* whh_b  = (const float*)d_in[7];
  const float* b_b    = (const float*)d_in[8];
  const float* h10    = (const float*)d_in[9];
  const float* c10    = (const float*)d_in[10];
  const float* wihs   = (const float*)d_in[11];
  const float* whhs   = (const float*)d_in[12];
  const float* bs     = (const float*)d_in[13];
  const float* h20    = (const float*)d_in[14];
  const float* c20    = (const float*)d_in[15];
  const float* Wtag   = (const float*)d_in[16];
  const float* btag   = (const float*)d_in[17];
  const float* trans  = (const float*)d_in[18];
  float* ws = (float*)d_ws;
  float* out = (float*)d_out;
  int* barbase = (int*)(ws + OFF_BAR);

  // zero barrier state (ws is poisoned 0xAA before every call) — k2 only
  hipMemsetAsync((void*)barbase, 0, BAR_INTS * sizeof(int), stream);

  k0<<<dim3(SS), dim3(256), 0, stream>>>(sentence, emb, ws + OFF_XT);

  K2A a2{ws + OFF_XT, ws + OFF_BI, wih_f, whh_f, b_f, wih_b, whh_b, b_b,
         h10, c10, lengths,
         ws + OFF_HF, ws + OFF_HB,
         barbase};
  k2<<<dim3(256), dim3(1024), 0, stream>>>(a2);

  // k4: init state, then one dispatch per super-step (stream-ordered).
  // Each dispatch also carries the fused k4b block (feats[t-2]).
  k4i<<<dim3(2), dim3(512), 0, stream>>>(h20, c20, ws + OFF_H0R, ws + OFF_H1H,
                                         ws + OFF_C0, ws + OFF_C1);
  K4S a4{ws + OFF_BI, ws + OFF_H0R, ws + OFF_H1H, wihs, whhs, bs,
         ws + OFF_C0, ws + OFF_C1,
         Wtag, btag, ws + OFF_FEATS};
  for (int t = 0; t <= SS + 1; ++t) {
    k4s<<<dim3(257), dim3(1024), 0, stream>>>(a4, t);
  }

  k5<<<dim3(BB), dim3(64), 0, stream>>>(ws + OFF_FEATS, trans, lengths, out);
}

// Round 12
// 10539.636 us; speedup vs baseline: 2.2179x; 2.2179x over previous
//
#include <hip/hip_runtime.h>
#include <cmath>

// ResLSTM+CRF on MI355X, fp32 vector-ALU implementation.
// R19 = EXACT revert to R15 (proven 10386 us) — terminal artifact.
// Session ledger: 17559 (R0 baseline) -> 12661 (R12: k4 as dispatch-per-step,
// no homemade barrier) -> 11196 (R14: k4s 16 waves/CU) -> 10386 (R15: k2
// widened to 16 waves + k4s c-hoist). Structural ceiling: k4's 513 dispatch
// boundaries (~6-7 us each) are the only remaining cost block, and every
// alternative sync primitive was hardware-tested and rejected: homemade
// persistent barrier (R7-R10: timing-sensitive numerics corruption; R11:
// 25 us/step even when stable), cooperative grid.sync (R13: ~60 us/sync),
// wider grids (R16: ramp > overlap), shadow-fused extra work (R18: low-
// occupancy block extends every dispatch's critical path).
//   k2: persistent BiLSTM, proven gbarC protocol, 1024 thr (R15).
//   k4: one dispatch per super-step, ordinary loads/stores, 1024 thr, c-hoist.

namespace {
constexpr int SS = 512;     // seq len
constexpr int BB = 64;      // batch
constexpr int EE = 256;     // embed dim
constexpr int HHd = 256;    // half hidden (bi-lstm)
constexpr int HD = 512;     // hidden (stack)
constexpr int NTAG = 22;
constexpr int TSTART = 20;
constexpr int TSTOP = 21;

// ws offsets (in floats) — IDENTICAL footprint to the proven layout.
constexpr size_t OFF_BI    = 0;                                      // [512][512][64] chunked
constexpr size_t OFF_H1H   = OFF_BI    + (size_t)SS * HD * BB;       // [513][512][64] chunked
constexpr size_t OFF_XT    = OFF_H1H   + (size_t)(SS + 1) * HD * BB; // [512][256][64]; dead after k2 -> k4 c-state
constexpr size_t OFF_FEATS = OFF_XT    + (size_t)SS * EE * BB;       // [512][22][64]
constexpr size_t OFF_H0R   = OFF_FEATS + (size_t)SS * NTAG * BB;     // [2][512][64] ping-pong
constexpr size_t OFF_HF    = OFF_H0R   + 2 * (size_t)HD * BB;        // [2][256][64] (k2, coherent)
constexpr size_t OFF_HB    = OFF_HF    + 2 * (size_t)HHd * BB;
constexpr size_t OFF_BAR   = OFF_HB    + 2 * (size_t)HHd * BB;       // barrier state (ints, k2 only)
constexpr int BAR_INTS = 1152;

// k4 c-state, carved from the dead xT region
constexpr size_t OFF_C0 = OFF_XT;                    // [512][64] chunked (cidx)
constexpr size_t OFF_C1 = OFF_XT + (size_t)HD * BB;  // [512][64] chunked
}

__device__ __forceinline__ int cidx(int k, int lane) {
  return ((k >> 2) << 8) + (lane << 2) + (k & 3);
}

// ---- k2-only coherence helpers (proven; unchanged) ----
__device__ __forceinline__ float4 cload4(const float4* p) {
  float4 r;
  asm volatile("global_load_dwordx4 %0, %1, off sc0 sc1" : "=v"(r) : "v"(p));
  return r;
}
__device__ __forceinline__ void vwait0() {
  asm volatile("s_waitcnt vmcnt(0)" ::: "memory");
}
__device__ __forceinline__ void cstore(float* p, float v) {
  __hip_atomic_store(p, v, __ATOMIC_RELAXED, __HIP_MEMORY_SCOPE_AGENT);
}

// Centralized-release device barrier (k2 only), no fences.
template <int NBLK>
__device__ __forceinline__ void gbarC(int* flags, int* release, int bid, int epoch) {
  __syncthreads();
  if (threadIdx.x == 0) {
    __hip_atomic_store(flags + bid, epoch + 1, __ATOMIC_RELAXED, __HIP_MEMORY_SCOPE_AGENT);
  }
  if (bid == 0) {
    if (threadIdx.x < 64) {
      constexpr int PER = NBLK / 64;
      bool ok;
      do {
        ok = true;
#pragma unroll
        for (int i = 0; i < PER; ++i) {
          ok = ok && (__hip_atomic_load(flags + threadIdx.x * PER + i, __ATOMIC_RELAXED,
                                        __HIP_MEMORY_SCOPE_AGENT) > epoch);
        }
      } while (__any(!ok));
      if (threadIdx.x == 0) {
        __hip_atomic_store(release, epoch + 1, __ATOMIC_RELAXED, __HIP_MEMORY_SCOPE_AGENT);
      }
    }
  } else {
    if (threadIdx.x == 0) {
      while (__hip_atomic_load(release, __ATOMIC_RELAXED, __HIP_MEMORY_SCOPE_AGENT) <= epoch) {
        __builtin_amdgcn_s_sleep(1);
      }
    }
  }
  __syncthreads();
}

__device__ __forceinline__ float sigm(float x) { return 1.f / (1.f + expf(-x)); }
__device__ __forceinline__ float comp4(float4 v, int w) {
  return (w == 0) ? v.x : (w == 1) ? v.y : (w == 2) ? v.z : v.w;
}

// K0: gather embeddings, transpose to chunked [t][e-chunk][lane][4]
__global__ __launch_bounds__(256) void k0(const int* __restrict__ sent,
                                          const float* __restrict__ emb,
                                          float* __restrict__ xT) {
  const int t = blockIdx.x;
  const int lane = threadIdx.x & 63;
  const int w = __builtin_amdgcn_readfirstlane(threadIdx.x >> 6); // 0..3
  __shared__ float tile[64][65];
  __shared__ int rows[64];
  if (threadIdx.x < 64) rows[threadIdx.x] = sent[(size_t)threadIdx.x * SS + t];
  __syncthreads();
  float4* xT4 = (float4*)xT;
  for (int e0 = 0; e0 < EE; e0 += 64) {
    for (int bb = 0; bb < 16; ++bb) {
      int b = bb * 4 + w;
      tile[b][lane] = emb[(size_t)rows[b] * EE + e0 + lane];
    }
    __syncthreads();
    for (int r = 0; r < 4; ++r) {
      int ecl = w * 4 + r;
      int ec = (e0 >> 2) + ecl;
      float4 v = make_float4(tile[lane][ecl * 4 + 0], tile[lane][ecl * 4 + 1],
                             tile[lane][ecl * 4 + 2], tile[lane][ecl * 4 + 3]);
      xT4[((size_t)t * 64 + ec) * 64 + lane] = v;
    }
    __syncthreads();
  }
}

struct K2A {
  const float* xT; float* bi;
  const float* wih_f; const float* whh_f; const float* b_f;
  const float* wih_b; const float* whh_b; const float* b_b;
  const float* h10; const float* c10; const int* lengths;
  float* hf; float* hb;
  int* bar;
};

// K2: BiLSTM. 256 blocks x 1024 thr (16 waves, 4/SIMD). PROVEN R15 structure.
__global__ __launch_bounds__(1024, 1) void k2(K2A a) {
  const int lane = threadIdx.x & 63;
  const int w = __builtin_amdgcn_readfirstlane((int)threadIdx.x >> 6); // 0..15
  const int d = (int)blockIdx.x >> 7;
  const int lb = (int)blockIdx.x & 127;
  int* flags = a.bar + d * 384;
  int* release = a.bar + d * 384 + 160;
  const int u0 = lb * 2;
  const float* wih = d ? a.wih_b : a.wih_f;
  const float* whh = d ? a.whh_b : a.whh_f;
  const float* bias = d ? a.b_b : a.b_f;
  float* hbuf = d ? a.hb : a.hf;

  __shared__ float lw[8 * 512];          // 16 KB: [r][z-k], r = g*2+ul
  __shared__ float4 part[16][2][64];     // 32 KB

  // stage weights: 1024 float4s, 1 per thread
  {
    int f4 = (int)threadIdx.x;           // 0..1023
    int r = f4 >> 7;                     // 128 f4 per row
    int kk = (f4 & 127) * 4;
    int g = r >> 1, ul = r & 1;
    int grow = g * HHd + u0 + ul;
    float4 v = (kk < 256) ? *(const float4*)(wih + (size_t)grow * 256 + kk)
                          : *(const float4*)(whh + (size_t)grow * 256 + (kk - 256));
    *(float4*)(lw + r * 512 + kk) = v;
  }

  const int len = a.lengths[lane];
  float c_st = 0.f, h_old = 0.f;
  if (w < 2) {
    int u = u0 + w;
    h_old = a.h10[d * 256 + u];
    c_st = a.c10[d * 256 + u];
    cstore(&hbuf[cidx(u, lane)], h_old);
    vwait0();
  }
  int ep = 0;
  gbarC<128>(flags, release, lb, ep); ep++;   // entry __syncthreads orders staging

  const int ks = w * 32;                 // z-slice start (0..480)
  const bool hpart = (w >= 8);
  const float4* lw4 = (const float4*)lw;
  int buf = 0;
  for (int step = 0; step < SS; ++step) {
    const int t = d ? (SS - 1 - step) : step;
    const float* actbase = hpart ? (hbuf + (size_t)buf * (HHd * 64))
                                 : (a.xT + (size_t)t * (EE * 64));
    const int ksl = hpart ? (ks - 256) : ks;
    const float4* p = (const float4*)actbase + (size_t)(ksl >> 2) * 64 + lane;
    float4 va[8];
    if (hpart) {
#pragma unroll
      for (int c = 0; c < 8; ++c) va[c] = cload4(p + (size_t)c * 64);
      vwait0();
    } else {
#pragma unroll
      for (int c = 0; c < 8; ++c) va[c] = p[(size_t)c * 64];
    }
    float acc[8] = {0, 0, 0, 0, 0, 0, 0, 0};
#pragma unroll
    for (int c = 0; c < 8; ++c) {
      float4 h = va[c];
#pragma unroll
      for (int r = 0; r < 8; ++r) {
        float4 wv = lw4[r * 128 + (ks >> 2) + c];   // broadcast ds_read_b128
        acc[r] = fmaf(h.x, wv.x, acc[r]);
        acc[r] = fmaf(h.y, wv.y, acc[r]);
        acc[r] = fmaf(h.z, wv.z, acc[r]);
        acc[r] = fmaf(h.w, wv.w, acc[r]);
      }
    }
    part[w][0][lane] = make_float4(acc[0], acc[1], acc[2], acc[3]);
    part[w][1][lane] = make_float4(acc[4], acc[5], acc[6], acc[7]);
    __syncthreads();
    if (w < 2) {
      // acc rows: [0..3] = {i.u0,i.u1,f.u0,f.u1}, [4..7] = {g.u0,g.u1,o.u0,o.u1}
      float qi = 0.f, qf = 0.f, qg = 0.f, qo = 0.f;
#pragma unroll
      for (int wv = 0; wv < 16; ++wv) {
        float4 p0 = part[wv][0][lane], p1 = part[wv][1][lane];
        qi += comp4(p0, w);  qf += comp4(p0, 2 + w);
        qg += comp4(p1, w);  qo += comp4(p1, 2 + w);
      }
      const int u = u0 + w;
      float gi = qi + bias[u];
      float gf = qf + bias[256 + u];
      float gg = qg + bias[512 + u];
      float go = qo + bias[768 + u];
      float i_ = sigm(gi), f_ = sigm(gf), o_ = sigm(go);
      float gn = tanhf(gg);
      float c2 = f_ * c_st + i_ * gn;
      float h2 = o_ * tanhf(c2);
      const bool m = (t < len);
      h2 = m ? h2 : h_old;
      c_st = m ? c2 : c_st;
      h_old = h2;
      cstore(&hbuf[(size_t)(buf ^ 1) * (HHd * 64) + cidx(u, lane)], h2);
      a.bi[(size_t)t * (HD * 64) + cidx(d * 256 + u, lane)] = m ? h2 : 0.f;
      vwait0();
    }
    buf ^= 1;
    gbarC<128>(flags, release, lb, ep); ep++;
  }
}

// K4i: seed h0r[0], h1h[0], c0, c1 from h20/c20 (re-run every call; ws poisoned).
__global__ __launch_bounds__(512) void k4i(const float* __restrict__ h20,
                                           const float* __restrict__ c20,
                                           float* __restrict__ h0r,
                                           float* __restrict__ h1h,
                                           float* __restrict__ c0,
                                           float* __restrict__ c1) {
  const int layer = blockIdx.x;          // 0..1
  const int u = threadIdx.x;             // 0..511
  const float hv = h20[layer * 512 + u];
  const float cv = c20[layer * 512 + u];
  float* hd = layer ? h1h : h0r;
  float* cd = layer ? c1 : c0;
#pragma unroll 4
  for (int lane = 0; lane < 64; ++lane) {
    hd[cidx(u, lane)] = hv;
    cd[cidx(u, lane)] = cv;
  }
}

struct K4S {
  const float* bi; float* h0r; float* h1h;
  const float* wihs; const float* whhs; const float* bs;
  float* c0; float* c1;
};

// K4s: ONE super-step. 256 blocks x 1024 thr (16 waves/CU, 4/SIMD).
// Block (layer = bid>>7, lb) owns units 4lb..4lb+3 (16 gate rows r = g*4+ul).
// 16 waves x 64-k slices: w<8 -> x-half (wih), w>=8 -> h-half (whh).
// Ordinary loads/stores; cross-step ordering from the dispatch boundary.
// c-state load hoisted to kernel start (hides L3 latency under matmul).
__global__ __launch_bounds__(1024, 1) void k4s(K4S a, int t) {
  const int layer = (int)blockIdx.x >> 7;
  if (layer == 0) { if (t >= SS) return; } else { if (t < 1) return; }
  const int lane = threadIdx.x & 63;
  const int w = __builtin_amdgcn_readfirstlane((int)threadIdx.x >> 6);  // 0..15
  const int lb = (int)blockIdx.x & 127;
  const int u0 = lb * 4;
  const float* wih = a.wihs + (size_t)layer * (2048 * 512);
  const float* whh = a.whhs + (size_t)layer * (2048 * 512);

  __shared__ float part[8][16][64];      // 32 KB

  // hoisted c-state load (consumed in the epilogue, ~matmul-length later)
  float* cst = layer ? a.c1 : a.c0;
  float c_st = 0.f;
  if (w < 4) c_st = cst[cidx(u0 + w, lane)];

  const int ks = (w & 7) * 64;           // k-slice start within the 512-k half
  const bool hpart = (w >= 8);
  const float* wsel = hpart ? whh : wih;
  const float* wr[16];
#pragma unroll
  for (int g = 0; g < 4; ++g)
#pragma unroll
    for (int ul = 0; ul < 4; ++ul)
      wr[g * 4 + ul] = wsel + (size_t)(g * HD + u0 + ul) * HD + ks;

  const float* actbase;
  if (layer == 0)
    actbase = hpart ? (a.h0r + (size_t)(t & 1) * (HD * 64))
                    : (a.bi + (size_t)t * (HD * 64));
  else
    actbase = hpart ? (a.h1h + (size_t)(t - 1) * (HD * 64))
                    : (a.h0r + (size_t)(t & 1) * (HD * 64));

  // load this wave's 64-k activation slice (16 float4s)
  const float4* p = (const float4*)actbase + (size_t)(ks >> 2) * 64 + lane;
  float4 va[16];
#pragma unroll
  for (int c = 0; c < 16; ++c) va[c] = p[(size_t)c * 64];

  float acc[16] = {0, 0, 0, 0, 0, 0, 0, 0, 0, 0, 0, 0, 0, 0, 0, 0};
#pragma unroll
  for (int c = 0; c < 16; ++c) {
    float4 h = va[c];
    const int k = c * 4;
#pragma unroll
    for (int r = 0; r < 16; ++r) {
      float4 wv = *(const float4*)(wr[r] + k);      // cached global (uniform)
      acc[r] = fmaf(h.x, wv.x, acc[r]);
      acc[r] = fmaf(h.y, wv.y, acc[r]);
      acc[r] = fmaf(h.z, wv.z, acc[r]);
      acc[r] = fmaf(h.w, wv.w, acc[r]);
    }
  }
  // 2-stage cross-wave reduction: waves 0-7 write, waves 8-15 add.
  if (w < 8) {
#pragma unroll
    for (int r = 0; r < 16; ++r) part[w][r][lane] = acc[r];
  }
  __syncthreads();
  if (w >= 8) {
#pragma unroll
    for (int r = 0; r < 16; ++r) part[w - 8][r][lane] += acc[r];
  }
  __syncthreads();
  if (w < 4) {
    float q[4];
#pragma unroll
    for (int g = 0; g < 4; ++g) {
      float s = 0.f;
#pragma unroll
      for (int sl = 0; sl < 8; ++sl) s += part[sl][g * 4 + w][lane];
      q[g] = s;
    }
    const int u = u0 + w;
    const float* bsl = a.bs + (size_t)layer * 2048;
    float gi = q[0] + bsl[u];
    float gf = q[1] + bsl[512 + u];
    float gg = q[2] + bsl[1024 + u];
    float go = q[3] + bsl[1536 + u];
    float i_ = sigm(gi), f_ = sigm(gf), o_ = sigm(go);
    float gn = tanhf(gg);
    float c2 = f_ * c_st + i_ * gn;
    float h2 = o_ * tanhf(c2);
    cst[cidx(u, lane)] = c2;
    if (layer == 0)
      a.h0r[(size_t)((t + 1) & 1) * (HD * 64) + cidx(u, lane)] = h2;
    else
      a.h1h[(size_t)t * (HD * 64) + cidx(u, lane)] = h2;
  }
}

// K4b: feats[t][j][b] = h1(t) . W_tag[j] + b_tag[j]
__global__ __launch_bounds__(256) void k4b(const float* __restrict__ h1h,
                                           const float* __restrict__ Wtag,
                                           const float* __restrict__ btag,
                                           float* __restrict__ feats) {
  const int t = blockIdx.x;
  const int lane = threadIdx.x & 63;
  const int w = __builtin_amdgcn_readfirstlane(threadIdx.x >> 6);
  const int j0 = w * 6;
  const float4* p = (const float4*)(h1h + (size_t)(t + 1) * (HD * 64)) + lane;
  const float* r[6];
  float acc[6];
#pragma unroll
  for (int jj = 0; jj < 6; ++jj) {
    int j = j0 + jj; if (j > 21) j = 21;
    r[jj] = Wtag + (size_t)j * HD;
    acc[jj] = btag[j];
  }
#pragma unroll 2
  for (int c = 0; c < 128; ++c) {
    float4 h = p[(size_t)c * 64];
    int k = c * 4;
#pragma unroll
    for (int jj = 0; jj < 6; ++jj) {
      acc[jj] = fmaf(h.x, r[jj][k], acc[jj]);
      acc[jj] = fmaf(h.y, r[jj][k + 1], acc[jj]);
      acc[jj] = fmaf(h.z, r[jj][k + 2], acc[jj]);
      acc[jj] = fmaf(h.w, r[jj][k + 3], acc[jj]);
    }
  }
#pragma unroll
  for (int jj = 0; jj < 6; ++jj) {
    int j = j0 + jj;
    if (j < NTAG) feats[((size_t)t * NTAG + j) * 64 + lane] = acc[jj];
  }
}

// K5: Viterbi decode, one block per batch element, backpointers in LDS.
__global__ __launch_bounds__(64) void k5(const float* __restrict__ feats,
                                         const float* __restrict__ trans,
                                         const int* __restrict__ lengths,
                                         float* __restrict__ out) {
  const int b = blockIdx.x;
  const int j = threadIdx.x;
  __shared__ float tr[NTAG * NTAG];
  __shared__ float sc[NTAG];
  __shared__ float term[NTAG];
  __shared__ unsigned char bp[SS - 1][NTAG];
  for (int i = j; i < NTAG * NTAG; i += 64) tr[i] = trans[i];
  const int len = lengths[b];
  float score = 0.f;
  __syncthreads();
  if (j < NTAG) {
    score = feats[(size_t)j * 64 + b] + tr[j * NTAG + TSTART];
    sc[j] = score;
  }
  __syncthreads();
  for (int t = 1; t < len; ++t) {
    float best = -3.4e38f; int bi_ = 0;
    if (j < NTAG) {
#pragma unroll
      for (int i = 0; i < NTAG; ++i) {
        float c = sc[i] + tr[j * NTAG + i];
        if (c > best) { best = c; bi_ = i; }   // strict > keeps first max
      }
      score = best + feats[((size_t)t * NTAG + j) * 64 + b];
      bp[t - 1][j] = (unsigned char)bi_;
    }
    __syncthreads();
    if (j < NTAG) sc[j] = score;
    __syncthreads();
  }
  if (j < NTAG) term[j] = score + tr[TSTOP * NTAG + j];
  __syncthreads();
  if (j == 0) {
    float bs = term[0]; int bt = 0;
    for (int i = 1; i < NTAG; ++i) if (term[i] > bs) { bs = term[i]; bt = i; }
    out[b] = bs;
    int tag = bt;
    for (int t = SS - 1; t >= 1; --t) {
      out[64 + (size_t)b * SS + t] = (float)tag;
      if (t < len) tag = bp[t - 1][tag];
    }
    out[64 + (size_t)b * SS + 0] = (float)tag;
  }
}

extern "C" void kernel_launch(void* const* d_in, const int* in_sizes, int n_in,
                              void* d_out, int out_size, void* d_ws, size_t ws_size,
                              hipStream_t stream) {
  const int* sentence = (const int*)d_in[0];
  const int* lengths  = (const int*)d_in[1];
  const float* emb    = (const float*)d_in[2];
  const float* wih_f  = (const float*)d_in[3];
  const float* whh_f  = (const float*)d_in[4];
  const float* b_f    = (const float*)d_in[5];
  const float* wih_b  = (const float*)d_in[6];
  const float* whh_b  = (const float*)d_in[7];
  const float* b_b    = (const float*)d_in[8];
  const float* h10    = (const float*)d_in[9];
  const float* c10    = (const float*)d_in[10];
  const float* wihs   = (const float*)d_in[11];
  const float* whhs   = (const float*)d_in[12];
  const float* bs     = (const float*)d_in[13];
  const float* h20    = (const float*)d_in[14];
  const float* c20    = (const float*)d_in[15];
  const float* Wtag   = (const float*)d_in[16];
  const float* btag   = (const float*)d_in[17];
  const float* trans  = (const float*)d_in[18];
  float* ws = (float*)d_ws;
  float* out = (float*)d_out;
  int* barbase = (int*)(ws + OFF_BAR);

  // zero barrier state (ws is poisoned 0xAA before every call) — k2 only
  hipMemsetAsync((void*)barbase, 0, BAR_INTS * sizeof(int), stream);

  k0<<<dim3(SS), dim3(256), 0, stream>>>(sentence, emb, ws + OFF_XT);

  K2A a2{ws + OFF_XT, ws + OFF_BI, wih_f, whh_f, b_f, wih_b, whh_b, b_b,
         h10, c10, lengths,
         ws + OFF_HF, ws + OFF_HB,
         barbase};
  k2<<<dim3(256), dim3(1024), 0, stream>>>(a2);

  // k4: init state, then one dispatch per super-step (stream-ordered).
  k4i<<<dim3(2), dim3(512), 0, stream>>>(h20, c20, ws + OFF_H0R, ws + OFF_H1H,
                                         ws + OFF_C0, ws + OFF_C1);
  K4S a4{ws + OFF_BI, ws + OFF_H0R, ws + OFF_H1H, wihs, whhs, bs,
         ws + OFF_C0, ws + OFF_C1};
  for (int t = 0; t <= SS; ++t) {
    k4s<<<dim3(256), dim3(1024), 0, stream>>>(a4, t);
  }

  k4b<<<dim3(SS), dim3(256), 0, stream>>>(ws + OFF_H1H, Wtag, btag, ws + OFF_FEATS);
  k5<<<dim3(BB), dim3(64), 0, stream>>>(ws + OFF_FEATS, trans, lengths, out);
}